// Round 5
// baseline (171.751 us; speedup 1.0000x reference)
//
#include <hip/hip_runtime.h>
#include <hip/hip_cooperative_groups.h>
#include <math.h>

namespace cg = cooperative_groups;

#define N_PIX 2304   // 48*48
#define CDIM  256
#define KDIM  2048
#define TOPK  204

typedef __attribute__((ext_vector_type(8))) short bf16x8;
typedef __attribute__((ext_vector_type(4))) float f32x4;

__device__ __forceinline__ unsigned short f2bf(float f) {
    unsigned u = __float_as_uint(f);
    unsigned r = u + 0x7FFFu + ((u >> 16) & 1u);
    return (unsigned short)(r >> 16);
}
__device__ __forceinline__ float bf2f(unsigned short h) {
    return __uint_as_float((unsigned)h << 16);
}

__device__ __forceinline__ void gload16(const void* g, void* l) {
    __builtin_amdgcn_global_load_lds((const __attribute__((address_space(1))) void*)g,
                                     (__attribute__((address_space(3))) void*)l,
                                     16, 0, 0);
}

// ================= Phase 0: prep (x-norm/xn/copy + feat-norm/fnorm/F2T[raw]) =================
// b in [0,68). LDS use <= 35072 B.
__device__ __forceinline__ void ph_prep(int b, int t, char* sm,
                                        const float* __restrict__ x,
                                        const float* __restrict__ feat,
                                        const float* __restrict__ label,
                                        float* __restrict__ out,
                                        unsigned short* __restrict__ xn,
                                        unsigned short* __restrict__ fnorm,
                                        unsigned short* __restrict__ F2T) {
    if (b < 36) {
        // ---- x branch: 64 pixels per block ----
        unsigned short* tile = (unsigned short*)sm;      // [256][66] bf16 = 33792 B
        float* part  = (float*)(sm + 33792);             // [4][64]
        float* rnloc = (float*)(sm + 34816);             // [64]
        int p0 = b * 64;
        #pragma unroll
        for (int i = 0; i < 64; ++i) {
            int idx = t + i * 256;
            int c = idx >> 6, pl = idx & 63;
            float v = x[c * N_PIX + p0 + pl];
            out[c * N_PIX + p0 + pl] = v;                // passthrough copy (exact f32)
            tile[c * 66 + pl] = f2bf(v);
        }
        __syncthreads();
        {
            int pixel = t & 63, q = t >> 6;
            float s = 0.f;
            #pragma unroll
            for (int i = 0; i < 64; ++i) {
                float v = bf2f(tile[(q * 64 + i) * 66 + pixel]);
                s = fmaf(v, v, s);
            }
            part[q * 64 + pixel] = s;
        }
        __syncthreads();
        if (t < 64) {
            float tt = part[t] + part[64 + t] + part[128 + t] + part[192 + t];
            rnloc[t] = 1.0f / fmaxf(sqrtf(tt), 1e-12f);
        }
        __syncthreads();
        {
            int p = t >> 2, cq = t & 3;
            float rn = rnloc[p];
            #pragma unroll
            for (int j = 0; j < 8; ++j) {
                bf16x8 pk;
                #pragma unroll
                for (int jj = 0; jj < 8; ++jj)
                    pk[jj] = (short)f2bf(bf2f(tile[(cq * 64 + j * 8 + jj) * 66 + p]) * rn);
                *(bf16x8*)(xn + (size_t)(p0 + p) * CDIM + cq * 64 + j * 8) = pk;
            }
        }
    } else {
        // ---- feat branch: 64 rows per block ----
        unsigned short* tile = (unsigned short*)sm;      // [64][264] bf16 = 33792 B
        int r0 = (b - 36) * 64;
        #pragma unroll
        for (int i = 0; i < 64; ++i)
            tile[i * 264 + t] = f2bf(feat[(size_t)(r0 + i) * CDIM + t]);
        __syncthreads();
        int row = t >> 2, q = t & 3;
        float s = 0.f;
        #pragma unroll
        for (int i = 0; i < 64; ++i) {
            float v = bf2f(tile[row * 264 + q * 64 + i]);
            s = fmaf(v, v, s);
        }
        s += __shfl_xor(s, 1, 64);
        s += __shfl_xor(s, 2, 64);
        float rn = 1.0f / fmaxf(sqrtf(s), 1e-12f);
        // fnorm (normalized, cosine-score operand)
        #pragma unroll
        for (int j = 0; j < 8; ++j) {
            bf16x8 pk;
            #pragma unroll
            for (int jj = 0; jj < 8; ++jj)
                pk[jj] = (short)f2bf(bf2f(tile[row * 264 + q * 64 + j * 8 + jj]) * rn);
            *(bf16x8*)(fnorm + (size_t)(r0 + row) * CDIM + q * 64 + j * 8) = pk;
        }
        __syncthreads();
        // F2T transposed: RAW feat (reference gathers un-normalized feat_units)
        {
            int rp = (t & 31) * 2, cg2 = t >> 5;
            #pragma unroll
            for (int i = 0; i < 32; ++i) {
                int c = i * 8 + cg2;
                unsigned u0 = tile[rp * 264 + c];
                unsigned u1 = tile[(rp + 1) * 264 + c];
                *(unsigned*)(F2T + (size_t)c * KDIM + r0 + rp) = u0 | (u1 << 16);
            }
        }
        {
            int ch = t >> 6, r = t & 63;
            F2T[(size_t)(256 + ch) * KDIM + r0 + r] = f2bf(label[(size_t)(r0 + r) * 4 + ch]);
        }
        #pragma unroll
        for (int i = 0; i < 15; ++i) {
            int idx = t + i * 256;
            int zr = idx >> 6, zc = idx & 63;
            F2T[(size_t)(260 + zr) * KDIM + r0 + zc] = 0;
        }
    }
}

// ================= Phase 1: bf16 MFMA GEMM1  score = xn @ fnorm^T =================
// b in [0,288): m0 = (b>>4)*128, n0 = (b&15)*128. LDS 32 KB.
__device__ __forceinline__ void ph_gemm1(int b, int t, char* smraw,
                                         const unsigned short* __restrict__ A,
                                         const unsigned short* __restrict__ B,
                                         float* __restrict__ C) {
    unsigned short* smA = (unsigned short*)smraw;             // [2][128*32]
    unsigned short* smB = (unsigned short*)(smraw + 16384);   // [2][128*32]
    int l = t & 63, w = t >> 6;
    int m0 = (b >> 4) * 128, n0 = (b & 15) * 128;
    int wr = w >> 1, wc = w & 1;

    f32x4 acc[4][4] = {};

    #pragma unroll
    for (int r = 0; r < 2; ++r) {
        int row = r * 64 + w * 16 + (l >> 2);
        int ch  = (l & 3) ^ ((row >> 1) & 3);
        gload16(A + (size_t)(m0 + row) * CDIM + ch * 8, &smA[(r * 64 + w * 16) * 32]);
        gload16(B + (size_t)(n0 + row) * CDIM + ch * 8, &smB[(r * 64 + w * 16) * 32]);
    }
    __syncthreads();

    for (int ks = 0; ks < 8; ++ks) {
        int cur = ks & 1;
        if (ks < 7) {
            int k0 = (ks + 1) * 32;
            #pragma unroll
            for (int r = 0; r < 2; ++r) {
                int row = r * 64 + w * 16 + (l >> 2);
                int ch  = (l & 3) ^ ((row >> 1) & 3);
                gload16(A + (size_t)(m0 + row) * CDIM + k0 + ch * 8,
                        &smA[(cur ^ 1) * 4096 + (r * 64 + w * 16) * 32]);
                gload16(B + (size_t)(n0 + row) * CDIM + k0 + ch * 8,
                        &smB[(cur ^ 1) * 4096 + (r * 64 + w * 16) * 32]);
            }
        }
        bf16x8 av[4], bv[4];
        #pragma unroll
        for (int mi = 0; mi < 4; ++mi) {
            int R = wr * 64 + mi * 16 + (l & 15);
            av[mi] = *(const bf16x8*)&smA[cur * 4096 + R * 32 + (((l >> 4) ^ ((R >> 1) & 3)) << 3)];
        }
        #pragma unroll
        for (int ni = 0; ni < 4; ++ni) {
            int R = wc * 64 + ni * 16 + (l & 15);
            bv[ni] = *(const bf16x8*)&smB[cur * 4096 + R * 32 + (((l >> 4) ^ ((R >> 1) & 3)) << 3)];
        }
        #pragma unroll
        for (int mi = 0; mi < 4; ++mi)
            #pragma unroll
            for (int ni = 0; ni < 4; ++ni)
                acc[mi][ni] = __builtin_amdgcn_mfma_f32_16x16x32_bf16(av[mi], bv[ni], acc[mi][ni], 0, 0, 0);
        __syncthreads();
    }

    #pragma unroll
    for (int mi = 0; mi < 4; ++mi)
        #pragma unroll
        for (int ni = 0; ni < 4; ++ni) {
            int rbase = m0 + wr * 64 + mi * 16 + (l >> 4) * 4;
            int cidx  = n0 + wc * 64 + ni * 16 + (l & 15);
            #pragma unroll
            for (int r = 0; r < 4; ++r)
                C[(size_t)(rbase + r) * KDIM + cidx] = acc[mi][ni][r];
        }
}

// ================= Phase 2: wave-local softmax + bisection top-204 -> Wm bf16 =================
// b in [0,288): 8 rows per block, 2 per wave. Zero barriers, zero LDS.
__device__ __forceinline__ void ph_select(int b, int t,
                                          const float* __restrict__ score,
                                          unsigned short* __restrict__ Wm) {
    int l = t & 63, w = t >> 6;
    #pragma unroll 1
    for (int rr = 0; rr < 2; ++rr) {
        int row = b * 8 + w * 2 + rr;
        const float* srow = score + (size_t)row * KDIM;

        float s[32];
        #pragma unroll
        for (int j = 0; j < 8; ++j) {
            float4 v = *(const float4*)(srow + j * 256 + l * 4);
            s[j * 4 + 0] = v.x; s[j * 4 + 1] = v.y; s[j * 4 + 2] = v.z; s[j * 4 + 3] = v.w;
        }

        float d = 0.f;
        #pragma unroll
        for (int j = 0; j < 32; ++j) d += __expf(s[j]);
        #pragma unroll
        for (int off = 32; off; off >>= 1) d += __shfl_xor(d, off, 64);
        float rd = 1.0f / d;

        float lo = -1.5f, hi = 1.5f;
        #pragma unroll 1
        for (int it = 0; it < 22; ++it) {
            float mid = 0.5f * (lo + hi);
            int c = 0;
            #pragma unroll
            for (int j = 0; j < 32; ++j) c += (s[j] > mid) ? 1 : 0;
            #pragma unroll
            for (int off = 32; off; off >>= 1) c += __shfl_xor(c, off, 64);
            if (c >= TOPK) lo = mid; else hi = mid;
        }

        #pragma unroll
        for (int j = 0; j < 8; ++j) {
            ushort4 pk;
            pk.x = (s[j*4+0] > lo) ? f2bf(__expf(s[j*4+0]) * rd) : (unsigned short)0;
            pk.y = (s[j*4+1] > lo) ? f2bf(__expf(s[j*4+1]) * rd) : (unsigned short)0;
            pk.z = (s[j*4+2] > lo) ? f2bf(__expf(s[j*4+2]) * rd) : (unsigned short)0;
            pk.w = (s[j*4+3] > lo) ? f2bf(__expf(s[j*4+3]) * rd) : (unsigned short)0;
            *(ushort4*)(Wm + (size_t)row * KDIM + j * 256 + l * 4) = pk;
        }
    }
}

// ================= Phase 3: GEMM2  out_xy^T = Wm(2304x2048) @ F2T(320x2048)^T =================
// b in [0,180): m0 = (b/5)*64, n0 = (b%5)*64. LDS 64 KB.
__device__ __forceinline__ void ph_gemm2(int b, int t, char* sm,
                                         const unsigned short* __restrict__ W,
                                         const unsigned short* __restrict__ F2T,
                                         float* __restrict__ out) {
    int l = t & 63, w = t >> 6;
    int m0 = (b / 5) * 64, n0 = (b % 5) * 64;
    char* wbase = sm + w * 16384;
    int   kb    = w * 512;

    f32x4 acc[4][4] = {};

    #pragma unroll
    for (int i = 0; i < 4; ++i) {
        int row = i * 16 + (l >> 2);
        int ch  = (l & 3) ^ ((row >> 1) & 3);
        gload16(W   + (size_t)(m0 + row) * KDIM + kb + ch * 8, wbase + i * 1024);
        gload16(F2T + (size_t)(n0 + row) * KDIM + kb + ch * 8, wbase + 8192 + i * 1024);
    }

    for (int ks = 0; ks < 16; ++ks) {
        int cur = ks & 1;
        if (ks < 15) {
            int koff = kb + (ks + 1) * 32;
            #pragma unroll
            for (int i = 0; i < 4; ++i) {
                int row = i * 16 + (l >> 2);
                int ch  = (l & 3) ^ ((row >> 1) & 3);
                gload16(W   + (size_t)(m0 + row) * KDIM + koff + ch * 8, wbase + (cur ^ 1) * 4096 + i * 1024);
                gload16(F2T + (size_t)(n0 + row) * KDIM + koff + ch * 8, wbase + 8192 + (cur ^ 1) * 4096 + i * 1024);
            }
            asm volatile("s_waitcnt vmcnt(8)" ::: "memory");
        } else {
            asm volatile("s_waitcnt vmcnt(0)" ::: "memory");
        }
        bf16x8 av[4], bv[4];
        #pragma unroll
        for (int mi = 0; mi < 4; ++mi) {
            int R = mi * 16 + (l & 15);
            av[mi] = *(const bf16x8*)(wbase + cur * 4096 + R * 64 + (((l >> 4) ^ ((R >> 1) & 3)) << 4));
        }
        #pragma unroll
        for (int ni = 0; ni < 4; ++ni) {
            int R = ni * 16 + (l & 15);
            bv[ni] = *(const bf16x8*)(wbase + 8192 + cur * 4096 + R * 64 + (((l >> 4) ^ ((R >> 1) & 3)) << 4));
        }
        #pragma unroll
        for (int mi = 0; mi < 4; ++mi)
            #pragma unroll
            for (int ni = 0; ni < 4; ++ni)
                acc[mi][ni] = __builtin_amdgcn_mfma_f32_16x16x32_bf16(av[mi], bv[ni], acc[mi][ni], 0, 0, 0);
    }

    __syncthreads();
    float* tl = (float*)sm;                 // [2][64][65] f32
    if (w >= 2) {
        float* dst = tl + (w - 2) * 64 * 65;
        #pragma unroll
        for (int mi = 0; mi < 4; ++mi)
            #pragma unroll
            for (int ni = 0; ni < 4; ++ni) {
                int rr2 = mi * 16 + (l >> 4) * 4;
                int cc  = ni * 16 + (l & 15);
                #pragma unroll
                for (int r = 0; r < 4; ++r)
                    dst[(rr2 + r) * 65 + cc] = acc[mi][ni][r];
            }
    }
    __syncthreads();
    if (w < 2) {
        float* dst = tl + w * 64 * 65;
        #pragma unroll
        for (int mi = 0; mi < 4; ++mi)
            #pragma unroll
            for (int ni = 0; ni < 4; ++ni) {
                int rr2 = mi * 16 + (l >> 4) * 4;
                int cc  = ni * 16 + (l & 15);
                #pragma unroll
                for (int r = 0; r < 4; ++r)
                    dst[(rr2 + r) * 65 + cc] += acc[mi][ni][r];
            }
    }
    __syncthreads();
    int pl = t & 63, cg2 = t >> 6;
    #pragma unroll
    for (int i = 0; i < 16; ++i) {
        int cc = cg2 * 16 + i;
        int c_out = n0 + cc;
        int orow;
        if (c_out < 256) orow = 256 + c_out;
        else if (c_out < 260) orow = 512 + (c_out - 256);
        else continue;
        out[(size_t)orow * N_PIX + m0 + pl] = tl[pl * 65 + cc] + tl[64 * 65 + pl * 65 + cc];
    }
}

// ================= Cooperative mega-kernel: all 4 phases, 3 grid syncs =================
__global__ __launch_bounds__(256, 2) void k_mega(const float* __restrict__ x,
                                                 const float* __restrict__ feat,
                                                 const float* __restrict__ label,
                                                 float* __restrict__ out,
                                                 unsigned short* __restrict__ xn,
                                                 unsigned short* __restrict__ fnorm,
                                                 unsigned short* __restrict__ F2T,
                                                 unsigned short* __restrict__ Wm,
                                                 float* __restrict__ score) {
    __shared__ __align__(16) char sm[65536];
    int b = blockIdx.x, t = threadIdx.x;
    cg::grid_group grid = cg::this_grid();

    if (b < 68) ph_prep(b, t, sm, x, feat, label, out, xn, fnorm, F2T);
    grid.sync();
    ph_gemm1(b, t, sm, xn, fnorm, score);
    grid.sync();
    ph_select(b, t, score, Wm);
    grid.sync();
    if (b < 180) ph_gemm2(b, t, sm, Wm, F2T, out);
}

// ================= Fallback wrappers (identical math, separate launches) =================
__global__ __launch_bounds__(256) void k_prep_f(const float* x, const float* feat, const float* label,
                                                float* out, unsigned short* xn, unsigned short* fnorm,
                                                unsigned short* F2T) {
    __shared__ __align__(16) char sm[36864];
    ph_prep(blockIdx.x, threadIdx.x, sm, x, feat, label, out, xn, fnorm, F2T);
}
__global__ __launch_bounds__(256) void k_gemm1_f(const unsigned short* A, const unsigned short* B, float* C) {
    __shared__ __align__(16) char sm[32768];
    ph_gemm1(blockIdx.x, threadIdx.x, sm, A, B, C);
}
__global__ __launch_bounds__(256) void k_select_f(const float* score, unsigned short* Wm) {
    ph_select(blockIdx.x, threadIdx.x, score, Wm);
}
__global__ __launch_bounds__(256) void k_gemm2_f(const unsigned short* W, const unsigned short* F2T, float* out) {
    __shared__ __align__(16) char sm[65536];
    ph_gemm2(blockIdx.x, threadIdx.x, sm, W, F2T, out);
}

extern "C" void kernel_launch(void* const* d_in, const int* in_sizes, int n_in,
                              void* d_out, int out_size, void* d_ws, size_t ws_size,
                              hipStream_t stream) {
    const float* x     = (const float*)d_in[0];   // (1,256,48,48)
    const float* feat  = (const float*)d_in[1];   // (2048,256)
    const float* label = (const float*)d_in[2];   // (2048,4)
    float* out   = (float*)d_out;                 // (1,516,48,48) then score
    float* score = out + 516 * N_PIX;             // (2304,2048)

    char* ws = (char*)d_ws;
    unsigned short* xn    = (unsigned short*)(ws);             // 2304*256*2 = 1179648
    unsigned short* fnorm = (unsigned short*)(ws + 1179648);   // 2048*256*2 = 1048576
    unsigned short* F2T   = (unsigned short*)(ws + 2228224);   // 320*2048*2 = 1310720
    unsigned short* Wm    = (unsigned short*)(ws + 3538944);   // 2304*2048*2 = 9437184

    void* args[] = {(void*)&x, (void*)&feat, (void*)&label, (void*)&out,
                    (void*)&xn, (void*)&fnorm, (void*)&F2T, (void*)&Wm, (void*)&score};
    hipError_t e = hipLaunchCooperativeKernel((const void*)k_mega, dim3(288), dim3(256),
                                              args, 0, stream);
    if (e != hipSuccess) {
        (void)hipGetLastError();   // clear sticky error; fall back to 4-kernel path
        k_prep_f  <<<68,  256, 0, stream>>>(x, feat, label, out, xn, fnorm, F2T);
        k_gemm1_f <<<288, 256, 0, stream>>>(xn, fnorm, score);
        k_select_f<<<288, 256, 0, stream>>>(score, Wm);
        k_gemm2_f <<<180, 256, 0, stream>>>(Wm, F2T, out);
    }
}

// Round 6
// 52.373 us; speedup vs baseline: 3.2794x; 3.2794x over previous
//
#include <hip/hip_runtime.h>
#include <math.h>

#define N_PIX 2304   // 48*48
#define CDIM  256
#define KDIM  2048
#define TOPK  204

typedef __attribute__((ext_vector_type(8))) short bf16x8;
typedef __attribute__((ext_vector_type(4))) float f32x4;

__device__ __forceinline__ unsigned short f2bf(float f) {
    unsigned u = __float_as_uint(f);
    unsigned r = u + 0x7FFFu + ((u >> 16) & 1u);
    return (unsigned short)(r >> 16);
}
__device__ __forceinline__ float bf2f(unsigned short h) {
    return __uint_as_float((unsigned)h << 16);
}

__device__ __forceinline__ void gload16(const void* g, void* l) {
    __builtin_amdgcn_global_load_lds((const __attribute__((address_space(1))) void*)g,
                                     (__attribute__((address_space(3))) void*)l,
                                     16, 0, 0);
}

// ================= Kernel 1: prep (x-norm/xn/copy + feat-norm/fnorm/F2T[raw]) =================
// 68 blocks. float4-vectorized staging.
__global__ __launch_bounds__(256) void k_prep(const float* __restrict__ x,
                                              const float* __restrict__ feat,
                                              const float* __restrict__ label,
                                              float* __restrict__ out,
                                              unsigned short* __restrict__ xn,
                                              unsigned short* __restrict__ fnorm,
                                              unsigned short* __restrict__ F2T) {
    __shared__ __align__(16) char sm[36864];
    int b = blockIdx.x, t = threadIdx.x;

    if (b < 36) {
        // ---- x branch: 64 pixels per block ----
        unsigned short* tile = (unsigned short*)sm;      // [256][68] bf16 = 34816 B (136B rows, 8B-aligned)
        float* part  = (float*)(sm + 34816);             // [4][64]
        float* rnloc = (float*)(sm + 35840);             // [64]
        int p0 = b * 64;
        // 4096 float4 groups: 16 iters x 256 threads
        #pragma unroll
        for (int i = 0; i < 16; ++i) {
            int g  = i * 256 + t;
            int c  = g >> 4;                 // channel
            int p4 = g & 15;                 // float4 index within 64-pixel row
            float4 v = *(const float4*)(x + (size_t)c * N_PIX + p0 + p4 * 4);
            *(float4*)(out + (size_t)c * N_PIX + p0 + p4 * 4) = v;   // exact passthrough
            ushort4 pk;
            pk.x = f2bf(v.x); pk.y = f2bf(v.y); pk.z = f2bf(v.z); pk.w = f2bf(v.w);
            *(ushort4*)&tile[c * 68 + p4 * 4] = pk;
        }
        __syncthreads();
        {
            int pixel = t & 63, q = t >> 6;
            float s = 0.f;
            #pragma unroll
            for (int i = 0; i < 64; ++i) {
                float v = bf2f(tile[(q * 64 + i) * 68 + pixel]);
                s = fmaf(v, v, s);
            }
            part[q * 64 + pixel] = s;
        }
        __syncthreads();
        if (t < 64) {
            float tt = part[t] + part[64 + t] + part[128 + t] + part[192 + t];
            rnloc[t] = 1.0f / fmaxf(sqrtf(tt), 1e-12f);
        }
        __syncthreads();
        {
            int p = t >> 2, cq = t & 3;
            float rn = rnloc[p];
            #pragma unroll
            for (int j = 0; j < 8; ++j) {
                bf16x8 pk;
                #pragma unroll
                for (int jj = 0; jj < 8; ++jj)
                    pk[jj] = (short)f2bf(bf2f(tile[(cq * 64 + j * 8 + jj) * 68 + p]) * rn);
                *(bf16x8*)(xn + (size_t)(p0 + p) * CDIM + cq * 64 + j * 8) = pk;
            }
        }
    } else {
        // ---- feat branch: 64 rows per block ----
        unsigned short* tile = (unsigned short*)sm;      // [64][264] bf16 = 33792 B (528B rows)
        int r0 = (b - 36) * 64;
        #pragma unroll
        for (int i = 0; i < 16; ++i) {
            int g  = i * 256 + t;
            int r  = g >> 6;                 // row
            int c4 = g & 63;                 // float4 index in 256-ch row
            float4 v = *(const float4*)(feat + (size_t)(r0 + r) * CDIM + c4 * 4);
            ushort4 pk;
            pk.x = f2bf(v.x); pk.y = f2bf(v.y); pk.z = f2bf(v.z); pk.w = f2bf(v.w);
            *(ushort4*)&tile[r * 264 + c4 * 4] = pk;
        }
        __syncthreads();
        int row = t >> 2, q = t & 3;
        float s = 0.f;
        #pragma unroll
        for (int i = 0; i < 64; ++i) {
            float v = bf2f(tile[row * 264 + q * 64 + i]);
            s = fmaf(v, v, s);
        }
        s += __shfl_xor(s, 1, 64);
        s += __shfl_xor(s, 2, 64);
        float rn = 1.0f / fmaxf(sqrtf(s), 1e-12f);
        // fnorm (normalized, cosine-score operand)
        #pragma unroll
        for (int j = 0; j < 8; ++j) {
            bf16x8 pk;
            #pragma unroll
            for (int jj = 0; jj < 8; ++jj)
                pk[jj] = (short)f2bf(bf2f(tile[row * 264 + q * 64 + j * 8 + jj]) * rn);
            *(bf16x8*)(fnorm + (size_t)(r0 + row) * CDIM + q * 64 + j * 8) = pk;
        }
        __syncthreads();
        // F2T transposed: RAW feat (reference gathers un-normalized feat_units)
        {
            int rp = (t & 31) * 2, cg2 = t >> 5;
            #pragma unroll
            for (int i = 0; i < 32; ++i) {
                int c = i * 8 + cg2;
                unsigned u0 = tile[rp * 264 + c];
                unsigned u1 = tile[(rp + 1) * 264 + c];
                *(unsigned*)(F2T + (size_t)c * KDIM + r0 + rp) = u0 | (u1 << 16);
            }
        }
        {
            int ch = t >> 6, r = t & 63;
            F2T[(size_t)(256 + ch) * KDIM + r0 + r] = f2bf(label[(size_t)(r0 + r) * 4 + ch]);
        }
        #pragma unroll
        for (int i = 0; i < 15; ++i) {
            int idx = t + i * 256;
            int zr = idx >> 6, zc = idx & 63;
            F2T[(size_t)(260 + zr) * KDIM + r0 + zc] = 0;
        }
    }
}

// ================= Kernel 2: bf16 MFMA GEMM1  score = xn(2304x256) @ fnorm(2048x256)^T =================
__global__ __launch_bounds__(256) void k_gemm1(const unsigned short* __restrict__ A,
                                               const unsigned short* __restrict__ B,
                                               float* __restrict__ C) {
    __shared__ __align__(16) unsigned short smA[2][128 * 32];
    __shared__ __align__(16) unsigned short smB[2][128 * 32];
    int t = threadIdx.x, l = t & 63, w = t >> 6;
    int m0 = blockIdx.y * 128, n0 = blockIdx.x * 128;
    int wr = w >> 1, wc = w & 1;

    f32x4 acc[4][4] = {};

    #pragma unroll
    for (int r = 0; r < 2; ++r) {
        int row = r * 64 + w * 16 + (l >> 2);
        int ch  = (l & 3) ^ ((row >> 1) & 3);
        gload16(A + (size_t)(m0 + row) * CDIM + ch * 8, &smA[0][(r * 64 + w * 16) * 32]);
        gload16(B + (size_t)(n0 + row) * CDIM + ch * 8, &smB[0][(r * 64 + w * 16) * 32]);
    }
    __syncthreads();

    for (int ks = 0; ks < 8; ++ks) {
        int cur = ks & 1;
        if (ks < 7) {
            int k0 = (ks + 1) * 32;
            #pragma unroll
            for (int r = 0; r < 2; ++r) {
                int row = r * 64 + w * 16 + (l >> 2);
                int ch  = (l & 3) ^ ((row >> 1) & 3);
                gload16(A + (size_t)(m0 + row) * CDIM + k0 + ch * 8, &smA[cur ^ 1][(r * 64 + w * 16) * 32]);
                gload16(B + (size_t)(n0 + row) * CDIM + k0 + ch * 8, &smB[cur ^ 1][(r * 64 + w * 16) * 32]);
            }
        }
        bf16x8 av[4], bv[4];
        #pragma unroll
        for (int mi = 0; mi < 4; ++mi) {
            int R = wr * 64 + mi * 16 + (l & 15);
            av[mi] = *(const bf16x8*)&smA[cur][R * 32 + (((l >> 4) ^ ((R >> 1) & 3)) << 3)];
        }
        #pragma unroll
        for (int ni = 0; ni < 4; ++ni) {
            int R = wc * 64 + ni * 16 + (l & 15);
            bv[ni] = *(const bf16x8*)&smB[cur][R * 32 + (((l >> 4) ^ ((R >> 1) & 3)) << 3)];
        }
        #pragma unroll
        for (int mi = 0; mi < 4; ++mi)
            #pragma unroll
            for (int ni = 0; ni < 4; ++ni)
                acc[mi][ni] = __builtin_amdgcn_mfma_f32_16x16x32_bf16(av[mi], bv[ni], acc[mi][ni], 0, 0, 0);
        __syncthreads();
    }

    #pragma unroll
    for (int mi = 0; mi < 4; ++mi)
        #pragma unroll
        for (int ni = 0; ni < 4; ++ni) {
            int rbase = m0 + wr * 64 + mi * 16 + (l >> 4) * 4;
            int cidx  = n0 + wc * 64 + ni * 16 + (l & 15);
            #pragma unroll
            for (int r = 0; r < 4; ++r)
                C[(size_t)(rbase + r) * KDIM + cidx] = acc[mi][ni][r];
        }
}

// ================= Kernel 3: wave-per-row softmax + ballot-bisection top-204 -> Wm bf16 =================
// 576 blocks x 4 waves, one row per wave; zero barriers, zero LDS, scalar-pipe popcounts.
__global__ __launch_bounds__(256) void k_select(const float* __restrict__ score,
                                                unsigned short* __restrict__ Wm) {
    int t = threadIdx.x, l = t & 63, w = t >> 6;
    int row = blockIdx.x * 4 + w;
    const float* srow = score + (size_t)row * KDIM;

    float s[32];
    #pragma unroll
    for (int j = 0; j < 8; ++j) {
        float4 v = *(const float4*)(srow + j * 256 + l * 4);
        s[j * 4 + 0] = v.x; s[j * 4 + 1] = v.y; s[j * 4 + 2] = v.z; s[j * 4 + 3] = v.w;
    }

    // softmax denom (|score|<=~1: no max-shift needed)
    float d = 0.f;
    #pragma unroll
    for (int j = 0; j < 32; ++j) d += __expf(s[j]);
    #pragma unroll
    for (int off = 32; off; off >>= 1) d += __shfl_xor(d, off, 64);
    float rd = 1.0f / d;

    // 18-iter bisection; count via ballot+popc (scalar pipe), no shuffle reduce.
    // cosine scores: sigma ~ 1/16, top-10% threshold ~0.08 -> bracket [-0.25, 0.75] is generous.
    float lo = -0.25f, hi = 0.75f;
    #pragma unroll 1
    for (int it = 0; it < 18; ++it) {
        float mid = 0.5f * (lo + hi);
        int c = 0;
        #pragma unroll
        for (int j = 0; j < 32; ++j)
            c += (int)__popcll(__ballot(s[j] > mid));
        if (c >= TOPK) lo = mid; else hi = mid;
    }

    // masked softmax weights, bf16
    #pragma unroll
    for (int j = 0; j < 8; ++j) {
        ushort4 pk;
        pk.x = (s[j*4+0] > lo) ? f2bf(__expf(s[j*4+0]) * rd) : (unsigned short)0;
        pk.y = (s[j*4+1] > lo) ? f2bf(__expf(s[j*4+1]) * rd) : (unsigned short)0;
        pk.z = (s[j*4+2] > lo) ? f2bf(__expf(s[j*4+2]) * rd) : (unsigned short)0;
        pk.w = (s[j*4+3] > lo) ? f2bf(__expf(s[j*4+3]) * rd) : (unsigned short)0;
        *(ushort4*)(Wm + (size_t)row * KDIM + j * 256 + l * 4) = pk;
    }
}

// ================= Kernel 4: GEMM2  out_xy^T = Wm(2304x2048) @ F2T(320x2048)^T =================
__global__ __launch_bounds__(256) void k_gemm2(const unsigned short* __restrict__ W,
                                               const unsigned short* __restrict__ F2T,
                                               float* __restrict__ out) {
    __shared__ __align__(16) char sm[65536];
    int t = threadIdx.x, l = t & 63, w = t >> 6;
    int m0 = blockIdx.y * 64, n0 = blockIdx.x * 64;
    char* wbase = sm + w * 16384;
    int   kb    = w * 512;

    f32x4 acc[4][4] = {};

    #pragma unroll
    for (int i = 0; i < 4; ++i) {
        int row = i * 16 + (l >> 2);
        int ch  = (l & 3) ^ ((row >> 1) & 3);
        gload16(W   + (size_t)(m0 + row) * KDIM + kb + ch * 8, wbase + i * 1024);
        gload16(F2T + (size_t)(n0 + row) * KDIM + kb + ch * 8, wbase + 8192 + i * 1024);
    }

    for (int ks = 0; ks < 16; ++ks) {
        int cur = ks & 1;
        if (ks < 15) {
            int koff = kb + (ks + 1) * 32;
            #pragma unroll
            for (int i = 0; i < 4; ++i) {
                int row = i * 16 + (l >> 2);
                int ch  = (l & 3) ^ ((row >> 1) & 3);
                gload16(W   + (size_t)(m0 + row) * KDIM + koff + ch * 8, wbase + (cur ^ 1) * 4096 + i * 1024);
                gload16(F2T + (size_t)(n0 + row) * KDIM + koff + ch * 8, wbase + 8192 + (cur ^ 1) * 4096 + i * 1024);
            }
            asm volatile("s_waitcnt vmcnt(8)" ::: "memory");
        } else {
            asm volatile("s_waitcnt vmcnt(0)" ::: "memory");
        }
        bf16x8 av[4], bv[4];
        #pragma unroll
        for (int mi = 0; mi < 4; ++mi) {
            int R = mi * 16 + (l & 15);
            av[mi] = *(const bf16x8*)(wbase + cur * 4096 + R * 64 + (((l >> 4) ^ ((R >> 1) & 3)) << 4));
        }
        #pragma unroll
        for (int ni = 0; ni < 4; ++ni) {
            int R = ni * 16 + (l & 15);
            bv[ni] = *(const bf16x8*)(wbase + 8192 + cur * 4096 + R * 64 + (((l >> 4) ^ ((R >> 1) & 3)) << 4));
        }
        #pragma unroll
        for (int mi = 0; mi < 4; ++mi)
            #pragma unroll
            for (int ni = 0; ni < 4; ++ni)
                acc[mi][ni] = __builtin_amdgcn_mfma_f32_16x16x32_bf16(av[mi], bv[ni], acc[mi][ni], 0, 0, 0);
    }

    __syncthreads();
    float* tl = (float*)sm;                 // [2][64][65] f32
    if (w >= 2) {
        float* dst = tl + (w - 2) * 64 * 65;
        #pragma unroll
        for (int mi = 0; mi < 4; ++mi)
            #pragma unroll
            for (int ni = 0; ni < 4; ++ni) {
                int rr = mi * 16 + (l >> 4) * 4;
                int cc = ni * 16 + (l & 15);
                #pragma unroll
                for (int r = 0; r < 4; ++r)
                    dst[(rr + r) * 65 + cc] = acc[mi][ni][r];
            }
    }
    __syncthreads();
    if (w < 2) {
        float* dst = tl + w * 64 * 65;
        #pragma unroll
        for (int mi = 0; mi < 4; ++mi)
            #pragma unroll
            for (int ni = 0; ni < 4; ++ni) {
                int rr = mi * 16 + (l >> 4) * 4;
                int cc = ni * 16 + (l & 15);
                #pragma unroll
                for (int r = 0; r < 4; ++r)
                    dst[(rr + r) * 65 + cc] += acc[mi][ni][r];
            }
    }
    __syncthreads();
    int pl = t & 63, cg2 = t >> 6;
    #pragma unroll
    for (int i = 0; i < 16; ++i) {
        int cc = cg2 * 16 + i;
        int c_out = n0 + cc;
        int orow;
        if (c_out < 256) orow = 256 + c_out;
        else if (c_out < 260) orow = 512 + (c_out - 256);
        else continue;
        out[(size_t)orow * N_PIX + m0 + pl] = tl[pl * 65 + cc] + tl[64 * 65 + pl * 65 + cc];
    }
}

extern "C" void kernel_launch(void* const* d_in, const int* in_sizes, int n_in,
                              void* d_out, int out_size, void* d_ws, size_t ws_size,
                              hipStream_t stream) {
    const float* x     = (const float*)d_in[0];   // (1,256,48,48)
    const float* feat  = (const float*)d_in[1];   // (2048,256)
    const float* label = (const float*)d_in[2];   // (2048,4)
    float* out   = (float*)d_out;                 // (1,516,48,48) then score
    float* score = out + 516 * N_PIX;             // (2304,2048)

    char* ws = (char*)d_ws;
    unsigned short* xn    = (unsigned short*)(ws);             // 2304*256*2 = 1179648
    unsigned short* fnorm = (unsigned short*)(ws + 1179648);   // 2048*256*2 = 1048576
    unsigned short* F2T   = (unsigned short*)(ws + 2228224);   // 320*2048*2 = 1310720
    unsigned short* Wm    = (unsigned short*)(ws + 3538944);   // 2304*2048*2 = 9437184

    k_prep  <<<68,           256, 0, stream>>>(x, feat, label, out, xn, fnorm, F2T);
    k_gemm1 <<<dim3(16, 18), 256, 0, stream>>>(xn, fnorm, score);
    k_select<<<576,          256, 0, stream>>>(score, Wm);
    k_gemm2 <<<dim3(5, 36),  256, 0, stream>>>(Wm, F2T, out);
}

// Round 7
// 49.661 us; speedup vs baseline: 3.4585x; 1.0546x over previous
//
#include <hip/hip_runtime.h>
#include <math.h>

#define N_PIX 2304   // 48*48
#define CDIM  256
#define KDIM  2048
#define TOPK  204

typedef __attribute__((ext_vector_type(8))) short bf16x8;
typedef __attribute__((ext_vector_type(4))) float f32x4;

__device__ __forceinline__ unsigned short f2bf(float f) {
    unsigned u = __float_as_uint(f);
    unsigned r = u + 0x7FFFu + ((u >> 16) & 1u);
    return (unsigned short)(r >> 16);
}
__device__ __forceinline__ float bf2f(unsigned short h) {
    return __uint_as_float((unsigned)h << 16);
}

__device__ __forceinline__ void gload16(const void* g, void* l) {
    __builtin_amdgcn_global_load_lds((const __attribute__((address_space(1))) void*)g,
                                     (__attribute__((address_space(3))) void*)l,
                                     16, 0, 0);
}

// ================= Kernel 1: prep, 272 blocks (144 x-blocks of 16 px + 128 feat-blocks of 16 rows) =================
__global__ __launch_bounds__(256) void k_prep(const float* __restrict__ x,
                                              const float* __restrict__ feat,
                                              const float* __restrict__ label,
                                              float* __restrict__ out,
                                              unsigned short* __restrict__ xn,
                                              unsigned short* __restrict__ fnorm,
                                              unsigned short* __restrict__ F2T) {
    __shared__ __align__(16) char sm[12288];
    int b = blockIdx.x, t = threadIdx.x;

    if (b < 144) {
        // ---- x branch: 16 pixels per block ----
        unsigned short* tile = (unsigned short*)sm;      // [256][20] bf16, 40B rows (8B-aligned)
        float* part  = (float*)(sm + 10240);             // [16 cg][16 px]
        float* rnloc = (float*)(sm + 11264);             // [16]
        int p0 = b * 16;
        // 1024 float4 groups / 256 threads = 4 iters
        #pragma unroll
        for (int i = 0; i < 4; ++i) {
            int g  = i * 256 + t;
            int c  = g >> 2;                 // channel 0..255
            int p4 = g & 3;                  // float4 within 16-pixel row
            float4 v = *(const float4*)(x + (size_t)c * N_PIX + p0 + p4 * 4);
            *(float4*)(out + (size_t)c * N_PIX + p0 + p4 * 4) = v;   // exact passthrough
            ushort4 pk;
            pk.x = f2bf(v.x); pk.y = f2bf(v.y); pk.z = f2bf(v.z); pk.w = f2bf(v.w);
            *(ushort4*)&tile[c * 20 + p4 * 4] = pk;
        }
        __syncthreads();
        {
            int px = t & 15, cg = t >> 4;    // 16 ch-groups of 16
            float s = 0.f;
            #pragma unroll
            for (int i = 0; i < 16; ++i) {
                float v = bf2f(tile[(cg * 16 + i) * 20 + px]);
                s = fmaf(v, v, s);
            }
            part[cg * 16 + px] = s;
        }
        __syncthreads();
        if (t < 16) {
            float tt = 0.f;
            #pragma unroll
            for (int cg = 0; cg < 16; ++cg) tt += part[cg * 16 + t];
            rnloc[t] = 1.0f / fmaxf(sqrtf(tt), 1e-12f);
        }
        __syncthreads();
        {
            int px = t >> 4;
            float rn = rnloc[px];
            #pragma unroll
            for (int ji = 0; ji < 2; ++ji) {
                int j = (t & 15) + ji * 16;  // 32 chunks of 8 ch
                bf16x8 pk;
                #pragma unroll
                for (int jj = 0; jj < 8; ++jj)
                    pk[jj] = (short)f2bf(bf2f(tile[(j * 8 + jj) * 20 + px]) * rn);
                *(bf16x8*)(xn + (size_t)(p0 + px) * CDIM + j * 8) = pk;
            }
        }
    } else {
        // ---- feat branch: 16 rows per block ----
        unsigned short* tile = (unsigned short*)sm;      // [16][264] bf16
        int r0 = (b - 144) * 16;
        #pragma unroll
        for (int i = 0; i < 4; ++i) {
            int g  = i * 256 + t;
            int r  = g >> 6;                 // row 0..15
            int c4 = g & 63;
            float4 v = *(const float4*)(feat + (size_t)(r0 + r) * CDIM + c4 * 4);
            ushort4 pk;
            pk.x = f2bf(v.x); pk.y = f2bf(v.y); pk.z = f2bf(v.z); pk.w = f2bf(v.w);
            *(ushort4*)&tile[r * 264 + c4 * 4] = pk;
        }
        __syncthreads();
        int row = t >> 4, q = t & 15;        // 16 lanes per row
        float s = 0.f;
        #pragma unroll
        for (int i = 0; i < 16; ++i) {
            float v = bf2f(tile[row * 264 + q * 16 + i]);
            s = fmaf(v, v, s);
        }
        s += __shfl_xor(s, 1, 64);
        s += __shfl_xor(s, 2, 64);
        s += __shfl_xor(s, 4, 64);
        s += __shfl_xor(s, 8, 64);
        float rn = 1.0f / fmaxf(sqrtf(s), 1e-12f);
        // fnorm row-major bf16 (normalized; cosine-score operand). thread t -> row t>>4, 2 chunks
        #pragma unroll
        for (int ji = 0; ji < 2; ++ji) {
            int j = q + ji * 16;
            bf16x8 pk;
            #pragma unroll
            for (int jj = 0; jj < 8; ++jj)
                pk[jj] = (short)f2bf(bf2f(tile[row * 264 + j * 8 + jj]) * rn);
            *(bf16x8*)(fnorm + (size_t)(r0 + row) * CDIM + j * 8) = pk;
        }
        __syncthreads();
        // F2T transposed: RAW feat. thread t owns column c=t, packs 2x ushort8 over rows
        {
            int c = t;
            #pragma unroll
            for (int h = 0; h < 2; ++h) {
                bf16x8 pk;
                #pragma unroll
                for (int r = 0; r < 8; ++r)
                    pk[r] = (short)tile[(h * 8 + r) * 264 + c];
                *(bf16x8*)(F2T + (size_t)c * KDIM + r0 + h * 8) = pk;
            }
        }
        // label rows 256..259 (raw)
        if (t < 64) {
            int ch = t >> 4, r = t & 15;
            F2T[(size_t)(256 + ch) * KDIM + r0 + r] = f2bf(label[(size_t)(r0 + r) * 4 + ch]);
        }
        // zero rows 260..319: 60 rows x 16 cols = 960 ushorts
        #pragma unroll
        for (int i = 0; i < 4; ++i) {
            int idx = i * 256 + t;
            if (idx < 960) {
                int zr = idx >> 4, zc = idx & 15;
                F2T[(size_t)(260 + zr) * KDIM + r0 + zc] = 0;
            }
        }
    }
}

// ================= Kernel 2: bf16 MFMA GEMM1  score = xn(2304x256) @ fnorm(2048x256)^T =================
// 64x128 tile, grid (16 n, 36 m) = 576 blocks, 4 waves (2x2), LDS 24 KB.
__global__ __launch_bounds__(256) void k_gemm1(const unsigned short* __restrict__ A,
                                               const unsigned short* __restrict__ B,
                                               float* __restrict__ C) {
    __shared__ __align__(16) unsigned short smA[2][64 * 32];    // 8 KB
    __shared__ __align__(16) unsigned short smB[2][128 * 32];   // 16 KB
    int t = threadIdx.x, l = t & 63, w = t >> 6;
    int m0 = blockIdx.y * 64, n0 = blockIdx.x * 128;
    int wr = w >> 1, wc = w & 1;

    f32x4 acc[2][4] = {};

    {   // stage buf0
        int rowA = w * 16 + (l >> 2);
        int chA  = (l & 3) ^ ((rowA >> 1) & 3);
        gload16(A + (size_t)(m0 + rowA) * CDIM + chA * 8, &smA[0][(w * 16) * 32]);
        #pragma unroll
        for (int i = 0; i < 2; ++i) {
            int rowB = i * 64 + w * 16 + (l >> 2);
            int chB  = (l & 3) ^ ((rowB >> 1) & 3);
            gload16(B + (size_t)(n0 + rowB) * CDIM + chB * 8, &smB[0][(i * 64 + w * 16) * 32]);
        }
    }
    __syncthreads();

    for (int ks = 0; ks < 8; ++ks) {
        int cur = ks & 1;
        if (ks < 7) {
            int k0 = (ks + 1) * 32;
            int rowA = w * 16 + (l >> 2);
            int chA  = (l & 3) ^ ((rowA >> 1) & 3);
            gload16(A + (size_t)(m0 + rowA) * CDIM + k0 + chA * 8, &smA[cur ^ 1][(w * 16) * 32]);
            #pragma unroll
            for (int i = 0; i < 2; ++i) {
                int rowB = i * 64 + w * 16 + (l >> 2);
                int chB  = (l & 3) ^ ((rowB >> 1) & 3);
                gload16(B + (size_t)(n0 + rowB) * CDIM + k0 + chB * 8, &smB[cur ^ 1][(i * 64 + w * 16) * 32]);
            }
        }
        bf16x8 av[2], bv[4];
        #pragma unroll
        for (int mi = 0; mi < 2; ++mi) {
            int R = wr * 32 + mi * 16 + (l & 15);
            av[mi] = *(const bf16x8*)&smA[cur][R * 32 + (((l >> 4) ^ ((R >> 1) & 3)) << 3)];
        }
        #pragma unroll
        for (int ni = 0; ni < 4; ++ni) {
            int R = wc * 64 + ni * 16 + (l & 15);
            bv[ni] = *(const bf16x8*)&smB[cur][R * 32 + (((l >> 4) ^ ((R >> 1) & 3)) << 3)];
        }
        #pragma unroll
        for (int mi = 0; mi < 2; ++mi)
            #pragma unroll
            for (int ni = 0; ni < 4; ++ni)
                acc[mi][ni] = __builtin_amdgcn_mfma_f32_16x16x32_bf16(av[mi], bv[ni], acc[mi][ni], 0, 0, 0);
        __syncthreads();
    }

    #pragma unroll
    for (int mi = 0; mi < 2; ++mi)
        #pragma unroll
        for (int ni = 0; ni < 4; ++ni) {
            int rbase = m0 + wr * 32 + mi * 16 + (l >> 4) * 4;
            int cidx  = n0 + wc * 64 + ni * 16 + (l & 15);
            #pragma unroll
            for (int r = 0; r < 4; ++r)
                C[(size_t)(rbase + r) * KDIM + cidx] = acc[mi][ni][r];
        }
}

// ================= Kernel 3: wave-per-row softmax + exp-domain ballot-bisection -> Wm bf16 =================
__global__ __launch_bounds__(256) void k_select(const float* __restrict__ score,
                                                unsigned short* __restrict__ Wm) {
    int t = threadIdx.x, l = t & 63, w = t >> 6;
    int row = blockIdx.x * 4 + w;
    const float* srow = score + (size_t)row * KDIM;

    // load + exp once; bisect and mask in exp-domain (monotone)
    float e[32];
    float d = 0.f;
    #pragma unroll
    for (int j = 0; j < 8; ++j) {
        float4 v = *(const float4*)(srow + j * 256 + l * 4);
        e[j * 4 + 0] = __expf(v.x); e[j * 4 + 1] = __expf(v.y);
        e[j * 4 + 2] = __expf(v.z); e[j * 4 + 3] = __expf(v.w);
        d += e[j*4+0] + e[j*4+1] + e[j*4+2] + e[j*4+3];
    }
    #pragma unroll
    for (int off = 32; off; off >>= 1) d += __shfl_xor(d, off, 64);
    float rd = 1.0f / d;

    // 18-iter bisection on e in [exp(-1), exp(1)]; count via ballot+popc (scalar pipe)
    float lo = 0.36f, hi = 2.72f;
    #pragma unroll 1
    for (int it = 0; it < 18; ++it) {
        float mid = 0.5f * (lo + hi);
        int c = 0;
        #pragma unroll
        for (int j = 0; j < 32; ++j)
            c += (int)__popcll(__ballot(e[j] > mid));
        if (c >= TOPK) lo = mid; else hi = mid;
    }

    #pragma unroll
    for (int j = 0; j < 8; ++j) {
        ushort4 pk;
        pk.x = (e[j*4+0] > lo) ? f2bf(e[j*4+0] * rd) : (unsigned short)0;
        pk.y = (e[j*4+1] > lo) ? f2bf(e[j*4+1] * rd) : (unsigned short)0;
        pk.z = (e[j*4+2] > lo) ? f2bf(e[j*4+2] * rd) : (unsigned short)0;
        pk.w = (e[j*4+3] > lo) ? f2bf(e[j*4+3] * rd) : (unsigned short)0;
        *(ushort4*)(Wm + (size_t)row * KDIM + j * 256 + l * 4) = pk;
    }
}

// ================= Kernel 4: GEMM2  out_xy^T = Wm(2304x2048) @ F2T(320x2048)^T =================
__global__ __launch_bounds__(256) void k_gemm2(const unsigned short* __restrict__ W,
                                               const unsigned short* __restrict__ F2T,
                                               float* __restrict__ out) {
    __shared__ __align__(16) char sm[65536];
    int t = threadIdx.x, l = t & 63, w = t >> 6;
    int m0 = blockIdx.y * 64, n0 = blockIdx.x * 64;
    char* wbase = sm + w * 16384;
    int   kb    = w * 512;

    f32x4 acc[4][4] = {};

    #pragma unroll
    for (int i = 0; i < 4; ++i) {
        int row = i * 16 + (l >> 2);
        int ch  = (l & 3) ^ ((row >> 1) & 3);
        gload16(W   + (size_t)(m0 + row) * KDIM + kb + ch * 8, wbase + i * 1024);
        gload16(F2T + (size_t)(n0 + row) * KDIM + kb + ch * 8, wbase + 8192 + i * 1024);
    }

    for (int ks = 0; ks < 16; ++ks) {
        int cur = ks & 1;
        if (ks < 15) {
            int koff = kb + (ks + 1) * 32;
            #pragma unroll
            for (int i = 0; i < 4; ++i) {
                int row = i * 16 + (l >> 2);
                int ch  = (l & 3) ^ ((row >> 1) & 3);
                gload16(W   + (size_t)(m0 + row) * KDIM + koff + ch * 8, wbase + (cur ^ 1) * 4096 + i * 1024);
                gload16(F2T + (size_t)(n0 + row) * KDIM + koff + ch * 8, wbase + 8192 + (cur ^ 1) * 4096 + i * 1024);
            }
            asm volatile("s_waitcnt vmcnt(8)" ::: "memory");
        } else {
            asm volatile("s_waitcnt vmcnt(0)" ::: "memory");
        }
        bf16x8 av[4], bv[4];
        #pragma unroll
        for (int mi = 0; mi < 4; ++mi) {
            int R = mi * 16 + (l & 15);
            av[mi] = *(const bf16x8*)(wbase + cur * 4096 + R * 64 + (((l >> 4) ^ ((R >> 1) & 3)) << 4));
        }
        #pragma unroll
        for (int ni = 0; ni < 4; ++ni) {
            int R = ni * 16 + (l & 15);
            bv[ni] = *(const bf16x8*)(wbase + 8192 + cur * 4096 + R * 64 + (((l >> 4) ^ ((R >> 1) & 3)) << 4));
        }
        #pragma unroll
        for (int mi = 0; mi < 4; ++mi)
            #pragma unroll
            for (int ni = 0; ni < 4; ++ni)
                acc[mi][ni] = __builtin_amdgcn_mfma_f32_16x16x32_bf16(av[mi], bv[ni], acc[mi][ni], 0, 0, 0);
    }

    __syncthreads();
    float* tl = (float*)sm;                 // [2][64][65] f32
    if (w >= 2) {
        float* dst = tl + (w - 2) * 64 * 65;
        #pragma unroll
        for (int mi = 0; mi < 4; ++mi)
            #pragma unroll
            for (int ni = 0; ni < 4; ++ni) {
                int rr = mi * 16 + (l >> 4) * 4;
                int cc = ni * 16 + (l & 15);
                #pragma unroll
                for (int r = 0; r < 4; ++r)
                    dst[(rr + r) * 65 + cc] = acc[mi][ni][r];
            }
    }
    __syncthreads();
    if (w < 2) {
        float* dst = tl + w * 64 * 65;
        #pragma unroll
        for (int mi = 0; mi < 4; ++mi)
            #pragma unroll
            for (int ni = 0; ni < 4; ++ni) {
                int rr = mi * 16 + (l >> 4) * 4;
                int cc = ni * 16 + (l & 15);
                #pragma unroll
                for (int r = 0; r < 4; ++r)
                    dst[(rr + r) * 65 + cc] += acc[mi][ni][r];
            }
    }
    __syncthreads();
    int pl = t & 63, cg2 = t >> 6;
    #pragma unroll
    for (int i = 0; i < 16; ++i) {
        int cc = cg2 * 16 + i;
        int c_out = n0 + cc;
        int orow;
        if (c_out < 256) orow = 256 + c_out;
        else if (c_out < 260) orow = 512 + (c_out - 256);
        else continue;
        out[(size_t)orow * N_PIX + m0 + pl] = tl[pl * 65 + cc] + tl[64 * 65 + pl * 65 + cc];
    }
}

extern "C" void kernel_launch(void* const* d_in, const int* in_sizes, int n_in,
                              void* d_out, int out_size, void* d_ws, size_t ws_size,
                              hipStream_t stream) {
    const float* x     = (const float*)d_in[0];   // (1,256,48,48)
    const float* feat  = (const float*)d_in[1];   // (2048,256)
    const float* label = (const float*)d_in[2];   // (2048,4)
    float* out   = (float*)d_out;                 // (1,516,48,48) then score
    float* score = out + 516 * N_PIX;             // (2304,2048)

    char* ws = (char*)d_ws;
    unsigned short* xn    = (unsigned short*)(ws);             // 2304*256*2 = 1179648
    unsigned short* fnorm = (unsigned short*)(ws + 1179648);   // 2048*256*2 = 1048576
    unsigned short* F2T   = (unsigned short*)(ws + 2228224);   // 320*2048*2 = 1310720
    unsigned short* Wm    = (unsigned short*)(ws + 3538944);   // 2304*2048*2 = 9437184

    k_prep  <<<272,          256, 0, stream>>>(x, feat, label, out, xn, fnorm, F2T);
    k_gemm1 <<<dim3(16, 36), 256, 0, stream>>>(xn, fnorm, score);
    k_select<<<576,          256, 0, stream>>>(score, Wm);
    k_gemm2 <<<dim3(5, 36),  256, 0, stream>>>(Wm, F2T, out);
}